// Round 5
// baseline (324.070 us; speedup 1.0000x reference)
//
#include <hip/hip_runtime.h>
#include <hip/hip_bf16.h>

// B=8, S=512 -> TOK=4096 tokens, D=1024, F=2048, H=16 heads, O=1.
#define TOK 4096
#define DD  1024
#define FF  2048
#define NH  16

typedef short bf16x8 __attribute__((ext_vector_type(8)));
typedef float f32x4  __attribute__((ext_vector_type(4)));

__device__ __forceinline__ float gelu_f(float x) {
  float u = 0.7978845608028654f * (x + 0.044715f * x * x * x);
  float e = __expf(2.0f * u);
  return 0.5f * x * (2.0f - 2.0f / (e + 1.0f));
}

// fp32 -> bf16 round-to-nearest-even
__device__ __forceinline__ unsigned short f2bf(float f) {
  union { float f; unsigned u; } v; v.f = f;
  unsigned r = v.u + 0x7FFF + ((v.u >> 16) & 1);
  return (unsigned short)(r >> 16);
}
__device__ __forceinline__ unsigned pack2(float a, float b) {
  return (unsigned)f2bf(a) | ((unsigned)f2bf(b) << 16);
}

// async global->LDS, 16 bytes per lane; LDS dst = wave-uniform base + lane*16
__device__ __forceinline__ void load_lds16(const void* g, void* l) {
  __builtin_amdgcn_global_load_lds(
      (const __attribute__((address_space(1))) void*)g,
      (__attribute__((address_space(3))) void*)l, 16, 0, 0);
}

// ---------------------------------------------------------------------------
// Fused preprocessing: one launch covers prep_w tiles, prep_x chunks and
// routing. All parts write disjoint memory; counts pre-zeroed by memset.
// ---------------------------------------------------------------------------
#define W1_TILES (16 * 16 * 32)   // h x kb(16) x fb(32)
#define WS_TILES (16 * 16)        // kb(16) x fb(16)
#define PW_BLKS  (W1_TILES + WS_TILES)   // 8448
#define PX_BLKS  (TOK * 128 / 256)       // 2048

__device__ void prep_w_body(
    int bid, const float* __restrict__ Ws, const float* __restrict__ W1,
    unsigned short* __restrict__ Wsp, unsigned short* __restrict__ W1p) {
  __shared__ unsigned short T[64][70];   // pad 70: phase-2 col reads ~conflict-free
  const float* src; unsigned short* dstBase; int stride, nt0, kc0;
  if (bid < W1_TILES) {
    int fb = bid & 31, kb = (bid >> 5) & 15, h = bid >> 9;
    src = W1 + ((size_t)h * DD + kb * 64) * FF + fb * 64;
    stride = FF;
    nt0 = h * 128 + fb * 4;          // global nt index (incl. head offset)
    kc0 = kb * 2;
    dstBase = W1p;
  } else {
    int b2 = bid - W1_TILES;
    int fb = b2 & 15, kb = b2 >> 4;
    src = Ws + (size_t)(kb * 64) * DD + fb * 64;
    stride = DD;
    nt0 = fb * 4;
    kc0 = kb * 2;
    dstBase = Wsp;
  }
  const int tid = threadIdx.x;
  // Phase 1: coalesced read of 64 rows x 64 cols fp32.
  {
    int r = tid >> 2, cq = (tid & 3) * 16;
    const float* p = src + (size_t)r * stride + cq;
#pragma unroll
    for (int i = 0; i < 4; ++i) {
      float4 v = *(const float4*)(p + i * 4);
      *(unsigned*)&T[r][cq + i * 4 + 0] = pack2(v.x, v.y);
      *(unsigned*)&T[r][cq + i * 4 + 2] = pack2(v.z, v.w);
    }
  }
  __syncthreads();
  // Phase 2: each thread emits 2 frag chunks (16B, coalesced stores).
#pragma unroll
  for (int cc = 0; cc < 2; ++cc) {
    int idx = tid + cc * 256;                 // (ntl*2 + kcl)*64 + lane
    int lane2 = idx & 63, kcl = (idx >> 6) & 1, ntl = idx >> 7;
    int n_local = ntl * 16 + (lane2 & 15);
    int r0 = kcl * 32 + (lane2 >> 4) * 8;
    unsigned short e[8];
#pragma unroll
    for (int j = 0; j < 8; ++j) e[j] = T[r0 + j][n_local];
    uint4 o;
    o.x = (unsigned)e[0] | ((unsigned)e[1] << 16);
    o.y = (unsigned)e[2] | ((unsigned)e[3] << 16);
    o.z = (unsigned)e[4] | ((unsigned)e[5] << 16);
    o.w = (unsigned)e[6] | ((unsigned)e[7] << 16);
    size_t chunk = ((size_t)(nt0 + ntl) * 32 + (kc0 + kcl)) * 64 + lane2;
    *(uint4*)(dstBase + chunk * 8) = o;
  }
}

__device__ void prep_x_body(
    int gid, const int* __restrict__ selfies, const int* __restrict__ tasks,
    const float* __restrict__ values, const int* __restrict__ pmask,
    const float* __restrict__ emb_s, const float* __restrict__ emb_t,
    const float* __restrict__ val_vec, unsigned short* __restrict__ Xb) {
  int kc = (gid & 127) * 8;
  int t  = gid >> 7;
  int sid = selfies[t], tsk = tasks[t];
  float v = values[t];
  float msk = pmask[t] ? 1.0f : 0.0f;
  const float* ps = emb_s + (size_t)sid * DD + kc;
  const float* pt = emb_t + (size_t)tsk * DD + kc;
  const float* pv = val_vec + kc;
  float r[8];
#pragma unroll
  for (int j = 0; j < 8; j += 4) {
    float4 a = *(const float4*)(ps + j);
    float4 b = *(const float4*)(pt + j);
    float4 c = *(const float4*)(pv + j);
    r[j + 0] = (a.x + b.x + v * c.x) * msk;
    r[j + 1] = (a.y + b.y + v * c.y) * msk;
    r[j + 2] = (a.z + b.z + v * c.z) * msk;
    r[j + 3] = (a.w + b.w + v * c.w) * msk;
  }
  uint4 o;
  o.x = pack2(r[0], r[1]); o.y = pack2(r[2], r[3]);
  o.z = pack2(r[4], r[5]); o.w = pack2(r[6], r[7]);
  *(uint4*)(Xb + (size_t)gid * 8) = o;
}

__global__ __launch_bounds__(256) void prep_all(
    const int* __restrict__ selfies, const int* __restrict__ tasks,
    const float* __restrict__ values, const int* __restrict__ pmask,
    const float* __restrict__ emb_s, const float* __restrict__ emb_t,
    const float* __restrict__ val_vec, const float* __restrict__ Ws,
    const float* __restrict__ W1, const float* __restrict__ b2,
    unsigned short* __restrict__ Xb, unsigned short* __restrict__ Wsp,
    unsigned short* __restrict__ W1p,
    int* __restrict__ counts, int* __restrict__ lists, float* __restrict__ out) {
  int bid = blockIdx.x;
  if (bid < PW_BLKS) {
    prep_w_body(bid, Ws, W1, Wsp, W1p);
  } else if (bid < PW_BLKS + PX_BLKS) {
    prep_x_body((bid - PW_BLKS) * 256 + threadIdx.x,
                selfies, tasks, values, pmask, emb_s, emb_t, val_vec, Xb);
  } else {
    int t = (bid - PW_BLKS - PX_BLKS) * 256 + threadIdx.x;
    if (t < TOK) {
      int task = tasks[t];
      if (task > 0) {
        int h = (task - 1) & (NH - 1);
        int pos = atomicAdd(&counts[h], 1);
        lists[h * TOK + pos] = t;
        out[t] = b2[h];
      } else {
        out[t] = 0.0f;
      }
    }
  }
}

// ---------------------------------------------------------------------------
// Stage 1: shared = gelu(X @ Ws + bs). Block = 64m x 128n, BK=32, 4 waves.
// QUAD-buffered LDS (48 KB -> 3 blocks/CU), 2-deep prefetch with counted
// s_waitcnt vmcnt(6), ONE s_barrier per K-step. (unchanged from round 3)
// ---------------------------------------------------------------------------
__global__ __launch_bounds__(256) void gemm1_mfma(
    const unsigned short* __restrict__ Xb, const unsigned short* __restrict__ Wsp,
    const float* __restrict__ bs, unsigned short* __restrict__ shared_bf) {
  __shared__ __align__(16) unsigned short As[4][4 * 64 * 8];   // 4 x 4 KB
  __shared__ __align__(16) unsigned short Bs[4][8 * 64 * 8];   // 4 x 8 KB

  const int tid = threadIdx.x;
  const int lane = tid & 63, w = tid >> 6;
  const int m0 = blockIdx.x * 64;
  const int n0 = blockIdx.y * 128;
  const int q = lane >> 4, c = lane & 15;

  const unsigned short* aSrc = Xb + (size_t)(m0 + w * 16 + c) * DD + q * 8;
  const unsigned short* bBase = Wsp + ((size_t)(blockIdx.y * 8 + w * 2)) * 32 * 512 + lane * 8;
  f32x4 acc[4][2] = {};

  // Pin epilogue loads BEFORE first stage so the vmcnt count stays exact.
  float bsv[2];
  bsv[0] = bs[n0 + w * 32 + c];
  bsv[1] = bs[n0 + w * 32 + 16 + c];
  asm volatile("" :: "v"(bsv[0]), "v"(bsv[1]));

  auto stage = [&](int buf, int kc2) {           // kc2 = K-step (32 k)
    load_lds16(aSrc + kc2 * 32, As[buf] + (size_t)(w * 64 + lane) * 8);
    const unsigned short* bk = bBase + kc2 * 512;
    load_lds16(bk,            Bs[buf] + (size_t)((w * 2 + 0) * 64 + lane) * 8);
    load_lds16(bk + 16384,    Bs[buf] + (size_t)((w * 2 + 1) * 64 + lane) * 8);
  };
  auto compute = [&](int buf) {
    bf16x8 a[4], b[2];
#pragma unroll
    for (int mt = 0; mt < 4; ++mt)
      a[mt] = *(const bf16x8*)(As[buf] + (size_t)(mt * 64 + lane) * 8);
#pragma unroll
    for (int t = 0; t < 2; ++t)
      b[t] = *(const bf16x8*)(Bs[buf] + (size_t)((w * 2 + t) * 64 + lane) * 8);
    __builtin_amdgcn_s_setprio(1);
#pragma unroll
    for (int mt = 0; mt < 4; ++mt)
#pragma unroll
      for (int t = 0; t < 2; ++t)
        acc[mt][t] = __builtin_amdgcn_mfma_f32_16x16x32_bf16(a[mt], b[t], acc[mt][t], 0, 0, 0);
    __builtin_amdgcn_s_setprio(0);
  };

  stage(0, 0);
  stage(1, 1);
  for (int i = 0; i < 30; ++i) {
    stage((i + 2) & 3, i + 2);                      // 2-deep prefetch
    asm volatile("s_waitcnt vmcnt(6)" ::: "memory"); // tile i landed
    __builtin_amdgcn_s_barrier();                    // publish i / retire oldest
    compute(i & 3);
    asm volatile("" ::: "memory");
  }
  asm volatile("s_waitcnt vmcnt(3)" ::: "memory");
  __builtin_amdgcn_s_barrier();
  compute(2);                                        // tile 30
  asm volatile("" ::: "memory");
  asm volatile("s_waitcnt vmcnt(0)" ::: "memory");
  __builtin_amdgcn_s_barrier();
  compute(3);                                        // tile 31

  // Epilogue: +bs, gelu, bf16, scatter u16 stores
#pragma unroll
  for (int mt = 0; mt < 4; ++mt)
#pragma unroll
    for (int t = 0; t < 2; ++t)
#pragma unroll
      for (int r = 0; r < 4; ++r) {
        int row = m0 + mt * 16 + q * 4 + r;
        int col = n0 + w * 32 + t * 16 + c;
        shared_bf[(size_t)row * DD + col] = f2bf(gelu_f(acc[mt][t][r] + bsv[t]));
      }
}

// ---------------------------------------------------------------------------
// Stage 2: per-head MLP. Block = 128 tokens x 128 F, BK=32, 4 waves,
// wave = 128m x 32n (8 mt x 2 nt) -> 16 MFMA per barrier. Grid 1024
// (4 m-blocks x 16 fc x 16 heads; capacity 512 tokens/head -- blocks with
// m0 >= count early-exit). XCD-pinned: 2 heads/XCD, all m-blocks of an
// fc-slice adjacent in dispatch. Quad-buffer (64 KB -> 2 blocks/CU),
// 2-deep prefetch, vmcnt(8) (4 loads/wave/stage), one barrier per K-step.
// ---------------------------------------------------------------------------
__global__ __launch_bounds__(256) void gemm2_mfma(
    const unsigned short* __restrict__ shared_bf, const unsigned short* __restrict__ W1p,
    const float* __restrict__ b1, const float* __restrict__ W2,
    const int* __restrict__ counts, const int* __restrict__ lists,
    float* __restrict__ out) {
  const int id = blockIdx.x;                      // 0..1023
  const int xcd = id & 7, local_ = id >> 3;       // local 0..127
  const int h = xcd + 8 * (local_ >> 6);
  const int rest = local_ & 63;
  const int fc = rest >> 2;                       // f0 = fc*128
  const int m0 = (rest & 3) * 128;                // capacity 512 tokens/head
  const int nt_h = counts[h];
  if (m0 >= nt_h) return;

  __shared__ __align__(16) unsigned short As[4][8 * 64 * 8];   // 4 x 8 KB
  __shared__ __align__(16) unsigned short Bs[4][8 * 64 * 8];   // 4 x 8 KB
  __shared__ int   stok[128];
  __shared__ float red[4][132];

  const int tid = threadIdx.x;
  const int lane = tid & 63, w = tid >> 6;
  const int q = lane >> 4, c = lane & 15;

  if (tid < 128) {
    int i = m0 + tid;
    stok[tid] = (i < nt_h) ? lists[h * TOK + i] : -1;
  }
  __syncthreads();   // full drain: stok loads complete before pipeline starts

  // A rows: wave w stages mt tiles {2w, 2w+1}; row-in-block = mt*16 + c.
  int tokrA = stok[(w * 2 + 0) * 16 + c];
  int tokrB = stok[(w * 2 + 1) * 16 + c];
  if (tokrA < 0) tokrA = 0;
  if (tokrB < 0) tokrB = 0;
  const unsigned short* aSrcA = shared_bf + (size_t)tokrA * DD + q * 8;
  const unsigned short* aSrcB = shared_bf + (size_t)tokrB * DD + q * 8;
  const unsigned short* bBase =
      W1p + ((size_t)h * 128 + fc * 8 + w * 2) * 32 * 512 + lane * 8;

  f32x4 acc[8][2] = {};

  // Pin epilogue loads BEFORE first stage (keeps vmcnt count exact).
  const float* b1h = b1 + (size_t)h * FF + fc * 128 + w * 32;
  const float* w2h = W2 + (size_t)h * FF + fc * 128 + w * 32;
  float b1v[2], w2v[2];
  b1v[0] = b1h[c];      b1v[1] = b1h[16 + c];
  w2v[0] = w2h[c];      w2v[1] = w2h[16 + c];
  asm volatile("" :: "v"(b1v[0]), "v"(b1v[1]), "v"(w2v[0]), "v"(w2v[1]));

  auto stage = [&](int buf, int kc2) {
    load_lds16(aSrcA + kc2 * 32, As[buf] + (size_t)((w * 2 + 0) * 64 + lane) * 8);
    load_lds16(aSrcB + kc2 * 32, As[buf] + (size_t)((w * 2 + 1) * 64 + lane) * 8);
    const unsigned short* bk = bBase + kc2 * 512;
    load_lds16(bk,            Bs[buf] + (size_t)((w * 2 + 0) * 64 + lane) * 8);
    load_lds16(bk + 16384,    Bs[buf] + (size_t)((w * 2 + 1) * 64 + lane) * 8);
  };
  auto compute = [&](int buf) {
    bf16x8 a[8], b[2];
#pragma unroll
    for (int mt = 0; mt < 8; ++mt)
      a[mt] = *(const bf16x8*)(As[buf] + (size_t)(mt * 64 + lane) * 8);
#pragma unroll
    for (int t = 0; t < 2; ++t)
      b[t] = *(const bf16x8*)(Bs[buf] + (size_t)((w * 2 + t) * 64 + lane) * 8);
    __builtin_amdgcn_s_setprio(1);
#pragma unroll
    for (int mt = 0; mt < 8; ++mt)
#pragma unroll
      for (int t = 0; t < 2; ++t)
        acc[mt][t] = __builtin_amdgcn_mfma_f32_16x16x32_bf16(a[mt], b[t], acc[mt][t], 0, 0, 0);
    __builtin_amdgcn_s_setprio(0);
  };

  stage(0, 0);
  stage(1, 1);
  for (int i = 0; i < 30; ++i) {
    stage((i + 2) & 3, i + 2);                       // 2-deep prefetch
    asm volatile("s_waitcnt vmcnt(8)" ::: "memory"); // tile i landed (4 ld/stage)
    __builtin_amdgcn_s_barrier();
    compute(i & 3);
    asm volatile("" ::: "memory");
  }
  asm volatile("s_waitcnt vmcnt(4)" ::: "memory");
  __builtin_amdgcn_s_barrier();
  compute(2);                                        // tile 30
  asm volatile("" ::: "memory");
  asm volatile("s_waitcnt vmcnt(0)" ::: "memory");
  __builtin_amdgcn_s_barrier();
  compute(3);                                        // tile 31

  // Epilogue: per lane cols n = fc*128 + w*32 + t*16 + c; rows mt*16+q*4+r.
#pragma unroll
  for (int mt = 0; mt < 8; ++mt)
#pragma unroll
    for (int r = 0; r < 4; ++r) {
      float s = 0.0f;
#pragma unroll
      for (int t = 0; t < 2; ++t)
        s += gelu_f(acc[mt][t][r] + b1v[t]) * w2v[t];
      s += __shfl_xor(s, 1);
      s += __shfl_xor(s, 2);
      s += __shfl_xor(s, 4);
      s += __shfl_xor(s, 8);
      if (c == 0) red[w][mt * 16 + q * 4 + r] = s;
    }
  __syncthreads();

  if (tid < 128) {
    int t = stok[tid];
    if (t >= 0) {
      float s = red[0][tid] + red[1][tid] + red[2][tid] + red[3][tid];
      atomicAdd(&out[t], s);
    }
  }
}

// ---------------------------------------------------------------------------
extern "C" void kernel_launch(void* const* d_in, const int* in_sizes, int n_in,
                              void* d_out, int out_size, void* d_ws, size_t ws_size,
                              hipStream_t stream) {
  const int*   selfies = (const int*)d_in[0];
  const int*   tasks   = (const int*)d_in[1];
  const float* values  = (const float*)d_in[2];
  const int*   pmask   = (const int*)d_in[3];
  const float* emb_s   = (const float*)d_in[4];
  const float* emb_t   = (const float*)d_in[5];
  const float* val_vec = (const float*)d_in[6];
  const float* Ws      = (const float*)d_in[7];
  const float* bs      = (const float*)d_in[8];
  const float* W1      = (const float*)d_in[9];
  const float* b1      = (const float*)d_in[10];
  const float* W2      = (const float*)d_in[11];
  const float* b2      = (const float*)d_in[12];
  float* out = (float*)d_out;

  // Workspace layout (all 256-B aligned):
  //   Xb        bf16 [4096][1024]            8 MB
  //   shared_bf bf16 [4096][1024]            8 MB
  //   Wsp       bf16 frag-major              2 MB
  //   W1p       bf16 frag-major             64 MB
  //   counts    int[16] ; lists int[16*4096]
  char* ws = (char*)d_ws;
  unsigned short* Xb        = (unsigned short*)ws;
  unsigned short* shared_bf = (unsigned short*)(ws + (8u << 20));
  unsigned short* Wsp       = (unsigned short*)(ws + (16u << 20));
  unsigned short* W1p       = (unsigned short*)(ws + (18u << 20));
  int* counts = (int*)(ws + (82u << 20));
  int* lists  = (int*)(ws + (82u << 20) + 256);

  hipMemsetAsync(counts, 0, NH * sizeof(int), stream);
  prep_all<<<PW_BLKS + PX_BLKS + TOK / 256, 256, 0, stream>>>(
      selfies, tasks, values, pmask, emb_s, emb_t, val_vec, Ws, W1, b2,
      Xb, Wsp, W1p, counts, lists, out);
  gemm1_mfma<<<dim3(TOK / 64, DD / 128), 256, 0, stream>>>(Xb, Wsp, bs, shared_bf);
  gemm2_mfma<<<1024, 256, 0, stream>>>(shared_bf, W1p, b1, W2,
                                       counts, lists, out);
}

// Round 6
// 304.392 us; speedup vs baseline: 1.0646x; 1.0646x over previous
//
#include <hip/hip_runtime.h>
#include <hip/hip_bf16.h>

// B=8, S=512 -> TOK=4096 tokens, D=1024, F=2048, H=16 heads, O=1.
#define TOK 4096
#define DD  1024
#define FF  2048
#define NH  16

typedef short bf16x8 __attribute__((ext_vector_type(8)));
typedef float f32x4  __attribute__((ext_vector_type(4)));

__device__ __forceinline__ float gelu_f(float x) {
  float u = 0.7978845608028654f * (x + 0.044715f * x * x * x);
  float e = __expf(2.0f * u);
  return 0.5f * x * (2.0f - 2.0f / (e + 1.0f));
}

// fp32 -> bf16 round-to-nearest-even
__device__ __forceinline__ unsigned short f2bf(float f) {
  union { float f; unsigned u; } v; v.f = f;
  unsigned r = v.u + 0x7FFF + ((v.u >> 16) & 1);
  return (unsigned short)(r >> 16);
}
__device__ __forceinline__ unsigned pack2(float a, float b) {
  return (unsigned)f2bf(a) | ((unsigned)f2bf(b) << 16);
}

// async global->LDS, 16 bytes per lane; LDS dst = wave-uniform base + lane*16
__device__ __forceinline__ void load_lds16(const void* g, void* l) {
  __builtin_amdgcn_global_load_lds(
      (const __attribute__((address_space(1))) void*)g,
      (__attribute__((address_space(3))) void*)l, 16, 0, 0);
}

// ---------------------------------------------------------------------------
// Weight tile converter: 64k x 64f fp32 tile -> bf16 frag-major chunks.
// Frag layout: chunk = (nt_g*32 + kc2)*64 + lane holds 8 elems,
//   elem j = W[kc2*32 + (lane>>4)*8 + j][nt*16 + (lane&15)].
// Phase 1 coalesced fp32 read -> padded LDS; phase 2 transposed 16B stores.
// ---------------------------------------------------------------------------
__device__ __forceinline__ void wtile_convert(
    const float* __restrict__ src, int stride,
    unsigned short* __restrict__ dstBase, int nt0, int kc0,
    unsigned short (*T)[70]) {
  const int tid = threadIdx.x;
  {
    int r = tid >> 2, cq = (tid & 3) * 16;
    const float* p = src + (size_t)r * stride + cq;
#pragma unroll
    for (int i = 0; i < 4; ++i) {
      float4 v = *(const float4*)(p + i * 4);
      *(unsigned*)&T[r][cq + i * 4 + 0] = pack2(v.x, v.y);
      *(unsigned*)&T[r][cq + i * 4 + 2] = pack2(v.z, v.w);
    }
  }
  __syncthreads();
#pragma unroll
  for (int cc = 0; cc < 2; ++cc) {
    int idx = tid + cc * 256;                 // (ntl*2 + kcl)*64 + lane
    int lane2 = idx & 63, kcl = (idx >> 6) & 1, ntl = idx >> 7;
    int n_local = ntl * 16 + (lane2 & 15);
    int r0 = kcl * 32 + (lane2 >> 4) * 8;
    unsigned short e[8];
#pragma unroll
    for (int j = 0; j < 8; ++j) e[j] = T[r0 + j][n_local];
    uint4 o;
    o.x = (unsigned)e[0] | ((unsigned)e[1] << 16);
    o.y = (unsigned)e[2] | ((unsigned)e[3] << 16);
    o.z = (unsigned)e[4] | ((unsigned)e[5] << 16);
    o.w = (unsigned)e[6] | ((unsigned)e[7] << 16);
    size_t chunk = ((size_t)(nt0 + ntl) * 32 + (kc0 + kcl)) * 64 + lane2;
    *(uint4*)(dstBase + chunk * 8) = o;
  }
}

// ---------------------------------------------------------------------------
// prep_small: Ws conversion (256 blocks) + prep_x (2048 blocks) + routing
// (16 blocks). Everything gemm1 needs; W1 conversion deferred to the fused
// gemm1 launch where it overlaps gemm1's MFMA work.
// ---------------------------------------------------------------------------
#define WS_BLKS 256
#define PX_BLKS (TOK * 128 / 256)   // 2048

__global__ __launch_bounds__(256) void prep_small(
    const int* __restrict__ selfies, const int* __restrict__ tasks,
    const float* __restrict__ values, const int* __restrict__ pmask,
    const float* __restrict__ emb_s, const float* __restrict__ emb_t,
    const float* __restrict__ val_vec, const float* __restrict__ Ws,
    const float* __restrict__ b2,
    unsigned short* __restrict__ Xb, unsigned short* __restrict__ Wsp,
    int* __restrict__ counts, int* __restrict__ lists, float* __restrict__ out) {
  __shared__ unsigned short T[64][70];
  int bid = blockIdx.x;
  if (bid < WS_BLKS) {
    int fb = bid & 15, kb = bid >> 4;
    wtile_convert(Ws + (size_t)(kb * 64) * DD + fb * 64, DD, Wsp,
                  fb * 4, kb * 2, T);
  } else if (bid < WS_BLKS + PX_BLKS) {
    int gid = (bid - WS_BLKS) * 256 + threadIdx.x;
    int kc = (gid & 127) * 8;
    int t  = gid >> 7;
    int sid = selfies[t], tsk = tasks[t];
    float v = values[t];
    float msk = pmask[t] ? 1.0f : 0.0f;
    const float* ps = emb_s + (size_t)sid * DD + kc;
    const float* pt = emb_t + (size_t)tsk * DD + kc;
    const float* pv = val_vec + kc;
    float r[8];
#pragma unroll
    for (int j = 0; j < 8; j += 4) {
      float4 a = *(const float4*)(ps + j);
      float4 b = *(const float4*)(pt + j);
      float4 c = *(const float4*)(pv + j);
      r[j + 0] = (a.x + b.x + v * c.x) * msk;
      r[j + 1] = (a.y + b.y + v * c.y) * msk;
      r[j + 2] = (a.z + b.z + v * c.z) * msk;
      r[j + 3] = (a.w + b.w + v * c.w) * msk;
    }
    uint4 o;
    o.x = pack2(r[0], r[1]); o.y = pack2(r[2], r[3]);
    o.z = pack2(r[4], r[5]); o.w = pack2(r[6], r[7]);
    *(uint4*)(Xb + (size_t)gid * 8) = o;
  } else {
    int t = (bid - WS_BLKS - PX_BLKS) * 256 + threadIdx.x;
    if (t < TOK) {
      int task = tasks[t];
      if (task > 0) {
        int h = (task - 1) & (NH - 1);
        int pos = atomicAdd(&counts[h], 1);
        lists[h * TOK + pos] = t;
        out[t] = b2[h];
      } else {
        out[t] = 0.0f;
      }
    }
  }
}

// ---------------------------------------------------------------------------
// Fused launch: blocks [0,512) run gemm1 (shared = gelu(X @ Ws + bs),
// 64m x 128n, BK=32, quad-buffered, vmcnt(6), one barrier/K-step -- the
// proven round-3 structure); blocks [512, 512+8192) convert W1 -> W1p
// frag-major. The two are independent; W1 conversion (the largest traffic
// item, ~192 MB) hides under gemm1's MFMA work instead of serializing.
// Shared 48 KB LDS arena (gemm1: As 16K + Bs 32K; w1prep: 9 KB tile).
// ---------------------------------------------------------------------------
#define G1_BLKS  512
#define W1_BLKS  (16 * 16 * 32)   // 8192: h x kb(16) x fb(32)

__device__ void gemm1_body(
    int bid, const unsigned short* __restrict__ Xb,
    const unsigned short* __restrict__ Wsp, const float* __restrict__ bs,
    unsigned short* __restrict__ shared_bf, char* smem) {
  unsigned short* As = (unsigned short*)smem;            // 4 bufs x 2048
  unsigned short* Bs = (unsigned short*)(smem + 16384);  // 4 bufs x 4096

  const int tid = threadIdx.x;
  const int lane = tid & 63, w = tid >> 6;
  const int m0 = (bid & 63) * 64;
  const int n0 = (bid >> 6) * 128;
  const int q = lane >> 4, c = lane & 15;

  const unsigned short* aSrc = Xb + (size_t)(m0 + w * 16 + c) * DD + q * 8;
  const unsigned short* bBase =
      Wsp + ((size_t)((bid >> 6) * 8 + w * 2)) * 32 * 512 + lane * 8;
  f32x4 acc[4][2] = {};

  // Pin epilogue loads BEFORE first stage so the vmcnt count stays exact.
  float bsv[2];
  bsv[0] = bs[n0 + w * 32 + c];
  bsv[1] = bs[n0 + w * 32 + 16 + c];
  asm volatile("" :: "v"(bsv[0]), "v"(bsv[1]));

  auto stage = [&](int buf, int kc2) {           // kc2 = K-step (32 k)
    load_lds16(aSrc + kc2 * 32, As + buf * 2048 + (size_t)(w * 64 + lane) * 8);
    const unsigned short* bk = bBase + kc2 * 512;
    load_lds16(bk,         Bs + buf * 4096 + (size_t)((w * 2 + 0) * 64 + lane) * 8);
    load_lds16(bk + 16384, Bs + buf * 4096 + (size_t)((w * 2 + 1) * 64 + lane) * 8);
  };
  auto compute = [&](int buf) {
    bf16x8 a[4], b[2];
#pragma unroll
    for (int mt = 0; mt < 4; ++mt)
      a[mt] = *(const bf16x8*)(As + buf * 2048 + (size_t)(mt * 64 + lane) * 8);
#pragma unroll
    for (int t = 0; t < 2; ++t)
      b[t] = *(const bf16x8*)(Bs + buf * 4096 + (size_t)((w * 2 + t) * 64 + lane) * 8);
    __builtin_amdgcn_s_setprio(1);
#pragma unroll
    for (int mt = 0; mt < 4; ++mt)
#pragma unroll
      for (int t = 0; t < 2; ++t)
        acc[mt][t] = __builtin_amdgcn_mfma_f32_16x16x32_bf16(a[mt], b[t], acc[mt][t], 0, 0, 0);
    __builtin_amdgcn_s_setprio(0);
  };

  stage(0, 0);
  stage(1, 1);
  for (int i = 0; i < 30; ++i) {
    stage((i + 2) & 3, i + 2);                      // 2-deep prefetch
    asm volatile("s_waitcnt vmcnt(6)" ::: "memory"); // tile i landed
    __builtin_amdgcn_s_barrier();                    // publish i / retire oldest
    compute(i & 3);
    asm volatile("" ::: "memory");
  }
  asm volatile("s_waitcnt vmcnt(3)" ::: "memory");
  __builtin_amdgcn_s_barrier();
  compute(2);                                        // tile 30
  asm volatile("" ::: "memory");
  asm volatile("s_waitcnt vmcnt(0)" ::: "memory");
  __builtin_amdgcn_s_barrier();
  compute(3);                                        // tile 31

  // Epilogue: +bs, gelu, bf16, scatter u16 stores
#pragma unroll
  for (int mt = 0; mt < 4; ++mt)
#pragma unroll
    for (int t = 0; t < 2; ++t)
#pragma unroll
      for (int r = 0; r < 4; ++r) {
        int row = m0 + mt * 16 + q * 4 + r;
        int col = n0 + w * 32 + t * 16 + c;
        shared_bf[(size_t)row * DD + col] = f2bf(gelu_f(acc[mt][t][r] + bsv[t]));
      }
}

__global__ __launch_bounds__(256) void gemm1_w1prep(
    const unsigned short* __restrict__ Xb, const unsigned short* __restrict__ Wsp,
    const float* __restrict__ bs, unsigned short* __restrict__ shared_bf,
    const float* __restrict__ W1, unsigned short* __restrict__ W1p) {
  __shared__ __align__(16) char smem[49152];
  int bid = blockIdx.x;
  if (bid < G1_BLKS) {
    gemm1_body(bid, Xb, Wsp, bs, shared_bf, smem);
  } else {
    int b = bid - G1_BLKS;                  // 0..8191
    int fb = b & 31, kb = (b >> 5) & 15, h = b >> 9;
    wtile_convert(W1 + ((size_t)h * DD + kb * 64) * FF + fb * 64, FF, W1p,
                  h * 128 + fb * 4, kb * 2,
                  (unsigned short (*)[70])smem);
  }
}

// ---------------------------------------------------------------------------
// Stage 2: per-head MLP. Block = 64 tokens x 128 F, BK=32, 4 waves.
// XCD-pinned 1-D grid 2048 (xcd = id&7 -> heads {xcd, xcd+8}); quad-buffer
// (48 KB -> 3 blocks/CU), 2-deep prefetch, vmcnt(6), one barrier per K-step.
// (exact round-3 version -- proven 304.2 us total)
// ---------------------------------------------------------------------------
__global__ __launch_bounds__(256) void gemm2_mfma(
    const unsigned short* __restrict__ shared_bf, const unsigned short* __restrict__ W1p,
    const float* __restrict__ b1, const float* __restrict__ W2,
    const int* __restrict__ counts, const int* __restrict__ lists,
    float* __restrict__ out) {
  const int id = blockIdx.x;
  const int xcd = id & 7, local_ = id >> 3;       // local 0..255
  const int h = xcd + 8 * (local_ >> 7);
  const int rest = local_ & 127;
  const int fc = rest & 15;                       // f0 = fc*128
  const int m0 = (rest >> 4) * 64;
  const int nt_h = counts[h];
  if (m0 >= nt_h) return;

  __shared__ __align__(16) unsigned short As[4][4 * 64 * 8];   // 4 x 4 KB
  __shared__ __align__(16) unsigned short Bs[4][8 * 64 * 8];   // 4 x 8 KB
  __shared__ int   stok[64];
  __shared__ float red[4][68];

  const int tid = threadIdx.x;
  const int lane = tid & 63, w = tid >> 6;
  const int q = lane >> 4, c = lane & 15;

  if (tid < 64) {
    int i = m0 + tid;
    stok[tid] = (i < nt_h) ? lists[h * TOK + i] : -1;
  }
  __syncthreads();   // full drain: stok loads complete before pipeline starts

  int tokr = stok[w * 16 + c];
  if (tokr < 0) tokr = 0;
  const unsigned short* aSrc = shared_bf + (size_t)tokr * DD + q * 8;
  const unsigned short* bBase =
      W1p + ((size_t)h * 128 + fc * 8 + w * 2) * 32 * 512 + lane * 8;

  f32x4 acc[4][2] = {};

  // Pin epilogue loads BEFORE first stage (keeps vmcnt count exact).
  const float* b1h = b1 + (size_t)h * FF + fc * 128 + w * 32;
  const float* w2h = W2 + (size_t)h * FF + fc * 128 + w * 32;
  float b1v[2], w2v[2];
  b1v[0] = b1h[c];      b1v[1] = b1h[16 + c];
  w2v[0] = w2h[c];      w2v[1] = w2h[16 + c];
  asm volatile("" :: "v"(b1v[0]), "v"(b1v[1]), "v"(w2v[0]), "v"(w2v[1]));

  auto stage = [&](int buf, int kc2) {
    load_lds16(aSrc + kc2 * 32, As[buf] + (size_t)(w * 64 + lane) * 8);
    const unsigned short* bk = bBase + kc2 * 512;
    load_lds16(bk,            Bs[buf] + (size_t)((w * 2 + 0) * 64 + lane) * 8);
    load_lds16(bk + 16384,    Bs[buf] + (size_t)((w * 2 + 1) * 64 + lane) * 8);
  };
  auto compute = [&](int buf) {
    bf16x8 a[4], b[2];
#pragma unroll
    for (int mt = 0; mt < 4; ++mt)
      a[mt] = *(const bf16x8*)(As[buf] + (size_t)(mt * 64 + lane) * 8);
#pragma unroll
    for (int t = 0; t < 2; ++t)
      b[t] = *(const bf16x8*)(Bs[buf] + (size_t)((w * 2 + t) * 64 + lane) * 8);
    __builtin_amdgcn_s_setprio(1);
#pragma unroll
    for (int mt = 0; mt < 4; ++mt)
#pragma unroll
      for (int t = 0; t < 2; ++t)
        acc[mt][t] = __builtin_amdgcn_mfma_f32_16x16x32_bf16(a[mt], b[t], acc[mt][t], 0, 0, 0);
    __builtin_amdgcn_s_setprio(0);
  };

  stage(0, 0);
  stage(1, 1);
  for (int i = 0; i < 30; ++i) {
    stage((i + 2) & 3, i + 2);
    asm volatile("s_waitcnt vmcnt(6)" ::: "memory");
    __builtin_amdgcn_s_barrier();
    compute(i & 3);
    asm volatile("" ::: "memory");
  }
  asm volatile("s_waitcnt vmcnt(3)" ::: "memory");
  __builtin_amdgcn_s_barrier();
  compute(2);
  asm volatile("" ::: "memory");
  asm volatile("s_waitcnt vmcnt(0)" ::: "memory");
  __builtin_amdgcn_s_barrier();
  compute(3);

  // Epilogue: per lane cols n = fc*128 + w*32 + t*16 + c
#pragma unroll
  for (int mt = 0; mt < 4; ++mt)
#pragma unroll
    for (int r = 0; r < 4; ++r) {
      float s = 0.0f;
#pragma unroll
      for (int t = 0; t < 2; ++t)
        s += gelu_f(acc[mt][t][r] + b1v[t]) * w2v[t];
      s += __shfl_xor(s, 1);
      s += __shfl_xor(s, 2);
      s += __shfl_xor(s, 4);
      s += __shfl_xor(s, 8);
      if (c == 0) red[w][mt * 16 + q * 4 + r] = s;
    }
  __syncthreads();

  if (tid < 64) {
    int t = stok[tid];
    if (t >= 0) {
      float s = red[0][tid] + red[1][tid] + red[2][tid] + red[3][tid];
      atomicAdd(&out[t], s);
    }
  }
}

// ---------------------------------------------------------------------------
extern "C" void kernel_launch(void* const* d_in, const int* in_sizes, int n_in,
                              void* d_out, int out_size, void* d_ws, size_t ws_size,
                              hipStream_t stream) {
  const int*   selfies = (const int*)d_in[0];
  const int*   tasks   = (const int*)d_in[1];
  const float* values  = (const float*)d_in[2];
  const int*   pmask   = (const int*)d_in[3];
  const float* emb_s   = (const float*)d_in[4];
  const float* emb_t   = (const float*)d_in[5];
  const float* val_vec = (const float*)d_in[6];
  const float* Ws      = (const float*)d_in[7];
  const float* bs      = (const float*)d_in[8];
  const float* W1      = (const float*)d_in[9];
  const float* b1      = (const float*)d_in[10];
  const float* W2      = (const float*)d_in[11];
  const float* b2      = (const float*)d_in[12];
  float* out = (float*)d_out;

  // Workspace layout (all 256-B aligned):
  //   Xb        bf16 [4096][1024]            8 MB
  //   shared_bf bf16 [4096][1024]            8 MB
  //   Wsp       bf16 frag-major              2 MB
  //   W1p       bf16 frag-major             64 MB
  //   counts    int[16] ; lists int[16*4096]
  char* ws = (char*)d_ws;
  unsigned short* Xb        = (unsigned short*)ws;
  unsigned short* shared_bf = (unsigned short*)(ws + (8u << 20));
  unsigned short* Wsp       = (unsigned short*)(ws + (16u << 20));
  unsigned short* W1p       = (unsigned short*)(ws + (18u << 20));
  int* counts = (int*)(ws + (82u << 20));
  int* lists  = (int*)(ws + (82u << 20) + 256);

  hipMemsetAsync(counts, 0, NH * sizeof(int), stream);
  prep_small<<<WS_BLKS + PX_BLKS + TOK / 256, 256, 0, stream>>>(
      selfies, tasks, values, pmask, emb_s, emb_t, val_vec, Ws, b2,
      Xb, Wsp, counts, lists, out);
  gemm1_w1prep<<<G1_BLKS + W1_BLKS, 256, 0, stream>>>(
      Xb, Wsp, bs, shared_bf, W1, W1p);
  gemm2_mfma<<<2048, 256, 0, stream>>>(shared_bf, W1p, b1, W2,
                                       counts, lists, out);
}

// Round 7
// 302.229 us; speedup vs baseline: 1.0723x; 1.0072x over previous
//
#include <hip/hip_runtime.h>
#include <hip/hip_bf16.h>

// B=8, S=512 -> TOK=4096 tokens, D=1024, F=2048, H=16 heads, O=1.
#define TOK 4096
#define DD  1024
#define FF  2048
#define NH  16

typedef short bf16x8 __attribute__((ext_vector_type(8)));
typedef float f32x4  __attribute__((ext_vector_type(4)));

__device__ __forceinline__ float gelu_f(float x) {
  float u = 0.7978845608028654f * (x + 0.044715f * x * x * x);
  float e = __expf(2.0f * u);
  return 0.5f * x * (2.0f - 2.0f / (e + 1.0f));
}

// fp32 -> bf16 round-to-nearest-even
__device__ __forceinline__ unsigned short f2bf(float f) {
  union { float f; unsigned u; } v; v.f = f;
  unsigned r = v.u + 0x7FFF + ((v.u >> 16) & 1);
  return (unsigned short)(r >> 16);
}
__device__ __forceinline__ unsigned pack2(float a, float b) {
  return (unsigned)f2bf(a) | ((unsigned)f2bf(b) << 16);
}

// async global->LDS, 16 bytes per lane; LDS dst = wave-uniform base + lane*16
__device__ __forceinline__ void load_lds16(const void* g, void* l) {
  __builtin_amdgcn_global_load_lds(
      (const __attribute__((address_space(1))) void*)g,
      (__attribute__((address_space(3))) void*)l, 16, 0, 0);
}

// ---------------------------------------------------------------------------
// Weight tile converter: 64k x 64f fp32 tile -> bf16 frag-major chunks.
// Frag layout: chunk = (nt_g*32 + kc2)*64 + lane holds 8 elems,
//   elem j = W[kc2*32 + (lane>>4)*8 + j][nt*16 + (lane&15)].
// Phase 1 coalesced fp32 read -> padded LDS; phase 2 transposed 16B stores.
// ---------------------------------------------------------------------------
__device__ __forceinline__ void wtile_convert(
    const float* __restrict__ src, int stride,
    unsigned short* __restrict__ dstBase, int nt0, int kc0,
    unsigned short (*T)[70]) {
  const int tid = threadIdx.x;
  {
    int r = tid >> 2, cq = (tid & 3) * 16;
    const float* p = src + (size_t)r * stride + cq;
#pragma unroll
    for (int i = 0; i < 4; ++i) {
      float4 v = *(const float4*)(p + i * 4);
      *(unsigned*)&T[r][cq + i * 4 + 0] = pack2(v.x, v.y);
      *(unsigned*)&T[r][cq + i * 4 + 2] = pack2(v.z, v.w);
    }
  }
  __syncthreads();
#pragma unroll
  for (int cc = 0; cc < 2; ++cc) {
    int idx = tid + cc * 256;                 // (ntl*2 + kcl)*64 + lane
    int lane2 = idx & 63, kcl = (idx >> 6) & 1, ntl = idx >> 7;
    int n_local = ntl * 16 + (lane2 & 15);
    int r0 = kcl * 32 + (lane2 >> 4) * 8;
    unsigned short e[8];
#pragma unroll
    for (int j = 0; j < 8; ++j) e[j] = T[r0 + j][n_local];
    uint4 o;
    o.x = (unsigned)e[0] | ((unsigned)e[1] << 16);
    o.y = (unsigned)e[2] | ((unsigned)e[3] << 16);
    o.z = (unsigned)e[4] | ((unsigned)e[5] << 16);
    o.w = (unsigned)e[6] | ((unsigned)e[7] << 16);
    size_t chunk = ((size_t)(nt0 + ntl) * 32 + (kc0 + kcl)) * 64 + lane2;
    *(uint4*)(dstBase + chunk * 8) = o;
  }
}

// ---------------------------------------------------------------------------
// prep_small: Ws conversion (256 blocks) + prep_x (2048 blocks) + routing.
// ---------------------------------------------------------------------------
#define WS_BLKS 256
#define PX_BLKS (TOK * 128 / 256)   // 2048

__global__ __launch_bounds__(256) void prep_small(
    const int* __restrict__ selfies, const int* __restrict__ tasks,
    const float* __restrict__ values, const int* __restrict__ pmask,
    const float* __restrict__ emb_s, const float* __restrict__ emb_t,
    const float* __restrict__ val_vec, const float* __restrict__ Ws,
    const float* __restrict__ b2,
    unsigned short* __restrict__ Xb, unsigned short* __restrict__ Wsp,
    int* __restrict__ counts, int* __restrict__ lists, float* __restrict__ out) {
  __shared__ unsigned short T[64][70];
  int bid = blockIdx.x;
  if (bid < WS_BLKS) {
    int fb = bid & 15, kb = bid >> 4;
    wtile_convert(Ws + (size_t)(kb * 64) * DD + fb * 64, DD, Wsp,
                  fb * 4, kb * 2, T);
  } else if (bid < WS_BLKS + PX_BLKS) {
    int gid = (bid - WS_BLKS) * 256 + threadIdx.x;
    int kc = (gid & 127) * 8;
    int t  = gid >> 7;
    int sid = selfies[t], tsk = tasks[t];
    float v = values[t];
    float msk = pmask[t] ? 1.0f : 0.0f;
    const float* ps = emb_s + (size_t)sid * DD + kc;
    const float* pt = emb_t + (size_t)tsk * DD + kc;
    const float* pv = val_vec + kc;
    float r[8];
#pragma unroll
    for (int j = 0; j < 8; j += 4) {
      float4 a = *(const float4*)(ps + j);
      float4 b = *(const float4*)(pt + j);
      float4 c = *(const float4*)(pv + j);
      r[j + 0] = (a.x + b.x + v * c.x) * msk;
      r[j + 1] = (a.y + b.y + v * c.y) * msk;
      r[j + 2] = (a.z + b.z + v * c.z) * msk;
      r[j + 3] = (a.w + b.w + v * c.w) * msk;
    }
    uint4 o;
    o.x = pack2(r[0], r[1]); o.y = pack2(r[2], r[3]);
    o.z = pack2(r[4], r[5]); o.w = pack2(r[6], r[7]);
    *(uint4*)(Xb + (size_t)gid * 8) = o;
  } else {
    int t = (bid - WS_BLKS - PX_BLKS) * 256 + threadIdx.x;
    if (t < TOK) {
      int task = tasks[t];
      if (task > 0) {
        int h = (task - 1) & (NH - 1);
        int pos = atomicAdd(&counts[h], 1);
        lists[h * TOK + pos] = t;
        out[t] = b2[h];
      } else {
        out[t] = 0.0f;
      }
    }
  }
}

// ---------------------------------------------------------------------------
// Fused launch: blocks [0,512) run gemm1 (64m x 128n, BK=32, quad-buffer,
// vmcnt(6), one barrier/K-step); blocks [512, 512+8192) convert W1 -> W1p.
// Shared 48 KB LDS arena. (unchanged from round 6)
// ---------------------------------------------------------------------------
#define G1_BLKS  512
#define W1_BLKS  (16 * 16 * 32)   // 8192: h x kb(16) x fb(32)

__device__ void gemm1_body(
    int bid, const unsigned short* __restrict__ Xb,
    const unsigned short* __restrict__ Wsp, const float* __restrict__ bs,
    unsigned short* __restrict__ shared_bf, char* smem) {
  unsigned short* As = (unsigned short*)smem;            // 4 bufs x 2048
  unsigned short* Bs = (unsigned short*)(smem + 16384);  // 4 bufs x 4096

  const int tid = threadIdx.x;
  const int lane = tid & 63, w = tid >> 6;
  const int m0 = (bid & 63) * 64;
  const int n0 = (bid >> 6) * 128;
  const int q = lane >> 4, c = lane & 15;

  const unsigned short* aSrc = Xb + (size_t)(m0 + w * 16 + c) * DD + q * 8;
  const unsigned short* bBase =
      Wsp + ((size_t)((bid >> 6) * 8 + w * 2)) * 32 * 512 + lane * 8;
  f32x4 acc[4][2] = {};

  // Pin epilogue loads BEFORE first stage so the vmcnt count stays exact.
  float bsv[2];
  bsv[0] = bs[n0 + w * 32 + c];
  bsv[1] = bs[n0 + w * 32 + 16 + c];
  asm volatile("" :: "v"(bsv[0]), "v"(bsv[1]));

  auto stage = [&](int buf, int kc2) {           // kc2 = K-step (32 k)
    load_lds16(aSrc + kc2 * 32, As + buf * 2048 + (size_t)(w * 64 + lane) * 8);
    const unsigned short* bk = bBase + kc2 * 512;
    load_lds16(bk,         Bs + buf * 4096 + (size_t)((w * 2 + 0) * 64 + lane) * 8);
    load_lds16(bk + 16384, Bs + buf * 4096 + (size_t)((w * 2 + 1) * 64 + lane) * 8);
  };
  auto compute = [&](int buf) {
    bf16x8 a[4], b[2];
#pragma unroll
    for (int mt = 0; mt < 4; ++mt)
      a[mt] = *(const bf16x8*)(As + buf * 2048 + (size_t)(mt * 64 + lane) * 8);
#pragma unroll
    for (int t = 0; t < 2; ++t)
      b[t] = *(const bf16x8*)(Bs + buf * 4096 + (size_t)((w * 2 + t) * 64 + lane) * 8);
    __builtin_amdgcn_s_setprio(1);
#pragma unroll
    for (int mt = 0; mt < 4; ++mt)
#pragma unroll
      for (int t = 0; t < 2; ++t)
        acc[mt][t] = __builtin_amdgcn_mfma_f32_16x16x32_bf16(a[mt], b[t], acc[mt][t], 0, 0, 0);
    __builtin_amdgcn_s_setprio(0);
  };

  stage(0, 0);
  stage(1, 1);
  for (int i = 0; i < 30; ++i) {
    stage((i + 2) & 3, i + 2);                      // 2-deep prefetch
    asm volatile("s_waitcnt vmcnt(6)" ::: "memory"); // tile i landed
    __builtin_amdgcn_s_barrier();                    // publish i / retire oldest
    compute(i & 3);
    asm volatile("" ::: "memory");
  }
  asm volatile("s_waitcnt vmcnt(3)" ::: "memory");
  __builtin_amdgcn_s_barrier();
  compute(2);                                        // tile 30
  asm volatile("" ::: "memory");
  asm volatile("s_waitcnt vmcnt(0)" ::: "memory");
  __builtin_amdgcn_s_barrier();
  compute(3);                                        // tile 31

  // Epilogue: +bs, gelu, bf16, scatter u16 stores
#pragma unroll
  for (int mt = 0; mt < 4; ++mt)
#pragma unroll
    for (int t = 0; t < 2; ++t)
#pragma unroll
      for (int r = 0; r < 4; ++r) {
        int row = m0 + mt * 16 + q * 4 + r;
        int col = n0 + w * 32 + t * 16 + c;
        shared_bf[(size_t)row * DD + col] = f2bf(gelu_f(acc[mt][t][r] + bsv[t]));
      }
}

__global__ __launch_bounds__(256) void gemm1_w1prep(
    const unsigned short* __restrict__ Xb, const unsigned short* __restrict__ Wsp,
    const float* __restrict__ bs, unsigned short* __restrict__ shared_bf,
    const float* __restrict__ W1, unsigned short* __restrict__ W1p) {
  __shared__ __align__(16) char smem[49152];
  int bid = blockIdx.x;
  if (bid < G1_BLKS) {
    gemm1_body(bid, Xb, Wsp, bs, shared_bf, smem);
  } else {
    int b = bid - G1_BLKS;                  // 0..8191
    int fb = b & 31, kb = (b >> 5) & 15, h = b >> 9;
    wtile_convert(W1 + ((size_t)h * DD + kb * 64) * FF + fb * 64, FF, W1p,
                  h * 128 + fb * 4, kb * 2,
                  (unsigned short (*)[70])smem);
  }
}

// ---------------------------------------------------------------------------
// Stage 2: per-head MLP. Block = 64 tokens x 128 F, BK=32, **8 waves**
// (512 threads): wave w owns n-slice nt=w (16 cols), 4 MFMA/step/wave.
// Same 48 KB quad-buffered LDS -> 3 blocks/CU x 8 waves = 24 waves/CU
// (2x the TLP of the 4-wave version -- latency hiding for W1p L2 misses).
// Staging per K-step: waves 0-3 load A-chunk + B-chunk (vmcnt 4/2/0),
// waves 4-7 load B-chunk only (vmcnt 2/1/0). One barrier per K-step;
// XCD-pinned grid 2048 as before.
// ---------------------------------------------------------------------------
__global__ __launch_bounds__(512) void gemm2_mfma(
    const unsigned short* __restrict__ shared_bf, const unsigned short* __restrict__ W1p,
    const float* __restrict__ b1, const float* __restrict__ W2,
    const int* __restrict__ counts, const int* __restrict__ lists,
    float* __restrict__ out) {
  const int id = blockIdx.x;
  const int xcd = id & 7, local_ = id >> 3;       // local 0..255
  const int h = xcd + 8 * (local_ >> 7);
  const int rest = local_ & 127;
  const int fc = rest & 15;                       // f0 = fc*128
  const int m0 = (rest >> 4) * 64;
  const int nt_h = counts[h];
  if (m0 >= nt_h) return;

  __shared__ __align__(16) unsigned short As[4][4 * 64 * 8];   // 4 x 4 KB
  __shared__ __align__(16) unsigned short Bs[4][8 * 64 * 8];   // 4 x 8 KB
  __shared__ int   stok[64];
  __shared__ float red[8][68];

  const int tid = threadIdx.x;
  const int lane = tid & 63, w = tid >> 6;        // w = 0..7
  const int q = lane >> 4, c = lane & 15;

  if (tid < 64) {
    int i = m0 + tid;
    stok[tid] = (i < nt_h) ? lists[h * TOK + i] : -1;
  }
  __syncthreads();   // full drain: stok loads complete before pipeline starts

  // A rows (waves 0-3 only): wave w stages rows w*16 + c.
  int tokr = stok[(w & 3) * 16 + c];
  if (tokr < 0) tokr = 0;
  const unsigned short* aSrc = shared_bf + (size_t)tokr * DD + q * 8;
  // B: wave w owns nt = fc*8 + w (16 cols).
  const unsigned short* bBase =
      W1p + ((size_t)h * 128 + fc * 8 + w) * 32 * 512 + lane * 8;

  f32x4 acc[4] = {};

  // Pin epilogue loads BEFORE first stage (keeps vmcnt count exact).
  float b1v = b1[(size_t)h * FF + fc * 128 + w * 16 + c];
  float w2v = W2[(size_t)h * FF + fc * 128 + w * 16 + c];
  asm volatile("" :: "v"(b1v), "v"(w2v));

  const bool loadsA = (w < 4);

  auto stage = [&](int buf, int kc2) {
    if (loadsA)
      load_lds16(aSrc + kc2 * 32, As[buf] + (size_t)(w * 64 + lane) * 8);
    load_lds16(bBase + kc2 * 512, Bs[buf] + (size_t)(w * 64 + lane) * 8);
  };
  auto compute = [&](int buf) {
    bf16x8 a[4], b;
#pragma unroll
    for (int mt = 0; mt < 4; ++mt)
      a[mt] = *(const bf16x8*)(As[buf] + (size_t)(mt * 64 + lane) * 8);
    b = *(const bf16x8*)(Bs[buf] + (size_t)(w * 64 + lane) * 8);
    __builtin_amdgcn_s_setprio(1);
#pragma unroll
    for (int mt = 0; mt < 4; ++mt)
      acc[mt] = __builtin_amdgcn_mfma_f32_16x16x32_bf16(a[mt], b, acc[mt], 0, 0, 0);
    __builtin_amdgcn_s_setprio(0);
  };

  stage(0, 0);
  stage(1, 1);
  for (int i = 0; i < 30; ++i) {
    stage((i + 2) & 3, i + 2);                       // 2-deep prefetch
    if (loadsA) { asm volatile("s_waitcnt vmcnt(4)" ::: "memory"); }
    else        { asm volatile("s_waitcnt vmcnt(2)" ::: "memory"); }
    __builtin_amdgcn_s_barrier();                    // tile i published
    compute(i & 3);
    asm volatile("" ::: "memory");
  }
  if (loadsA) { asm volatile("s_waitcnt vmcnt(2)" ::: "memory"); }
  else        { asm volatile("s_waitcnt vmcnt(1)" ::: "memory"); }
  __builtin_amdgcn_s_barrier();
  compute(2);                                        // tile 30
  asm volatile("" ::: "memory");
  asm volatile("s_waitcnt vmcnt(0)" ::: "memory");
  __builtin_amdgcn_s_barrier();
  compute(3);                                        // tile 31

  // Epilogue: wave w's cols n = fc*128 + w*16 + c; rows mt*16 + q*4 + r.
#pragma unroll
  for (int mt = 0; mt < 4; ++mt)
#pragma unroll
    for (int r = 0; r < 4; ++r) {
      float s = gelu_f(acc[mt][r] + b1v) * w2v;
      s += __shfl_xor(s, 1);
      s += __shfl_xor(s, 2);
      s += __shfl_xor(s, 4);
      s += __shfl_xor(s, 8);
      if (c == 0) red[w][mt * 16 + q * 4 + r] = s;
    }
  __syncthreads();

  if (tid < 64) {
    int t = stok[tid];
    if (t >= 0) {
      float s = 0.0f;
#pragma unroll
      for (int ww = 0; ww < 8; ++ww) s += red[ww][tid];
      atomicAdd(&out[t], s);
    }
  }
}

// ---------------------------------------------------------------------------
extern "C" void kernel_launch(void* const* d_in, const int* in_sizes, int n_in,
                              void* d_out, int out_size, void* d_ws, size_t ws_size,
                              hipStream_t stream) {
  const int*   selfies = (const int*)d_in[0];
  const int*   tasks   = (const int*)d_in[1];
  const float* values  = (const float*)d_in[2];
  const int*   pmask   = (const int*)d_in[3];
  const float* emb_s   = (const float*)d_in[4];
  const float* emb_t   = (const float*)d_in[5];
  const float* val_vec = (const float*)d_in[6];
  const float* Ws      = (const float*)d_in[7];
  const float* bs      = (const float*)d_in[8];
  const float* W1      = (const float*)d_in[9];
  const float* b1      = (const float*)d_in[10];
  const float* W2      = (const float*)d_in[11];
  const float* b2      = (const float*)d_in[12];
  float* out = (float*)d_out;

  // Workspace layout (all 256-B aligned):
  //   Xb        bf16 [4096][1024]            8 MB
  //   shared_bf bf16 [4096][1024]            8 MB
  //   Wsp       bf16 frag-major              2 MB
  //   W1p       bf16 frag-major             64 MB
  //   counts    int[16] ; lists int[16*4096]
  char* ws = (char*)d_ws;
  unsigned short* Xb        = (unsigned short*)ws;
  unsigned short* shared_bf = (unsigned short*)(ws + (8u << 20));
  unsigned short* Wsp       = (unsigned short*)(ws + (16u << 20));
  unsigned short* W1p       = (unsigned short*)(ws + (18u << 20));
  int* counts = (int*)(ws + (82u << 20));
  int* lists  = (int*)(ws + (82u << 20) + 256);

  hipMemsetAsync(counts, 0, NH * sizeof(int), stream);
  prep_small<<<WS_BLKS + PX_BLKS + TOK / 256, 256, 0, stream>>>(
      selfies, tasks, values, pmask, emb_s, emb_t, val_vec, Ws, b2,
      Xb, Wsp, counts, lists, out);
  gemm1_w1prep<<<G1_BLKS + W1_BLKS, 256, 0, stream>>>(
      Xb, Wsp, bs, shared_bf, W1, W1p);
  gemm2_mfma<<<2048, 512, 0, stream>>>(shared_bf, W1p, b1, W2,
                                       counts, lists, out);
}

// Round 8
// 301.783 us; speedup vs baseline: 1.0739x; 1.0015x over previous
//
#include <hip/hip_runtime.h>
#include <hip/hip_bf16.h>

// B=8, S=512 -> TOK=4096 tokens, D=1024, F=2048, H=16 heads, O=1.
#define TOK 4096
#define DD  1024
#define FF  2048
#define NH  16

typedef short bf16x8 __attribute__((ext_vector_type(8)));
typedef float f32x4  __attribute__((ext_vector_type(4)));

__device__ __forceinline__ float gelu_f(float x) {
  float u = 0.7978845608028654f * (x + 0.044715f * x * x * x);
  float e = __expf(2.0f * u);
  return 0.5f * x * (2.0f - 2.0f / (e + 1.0f));
}

// fp32 -> bf16 round-to-nearest-even
__device__ __forceinline__ unsigned short f2bf(float f) {
  union { float f; unsigned u; } v; v.f = f;
  unsigned r = v.u + 0x7FFF + ((v.u >> 16) & 1);
  return (unsigned short)(r >> 16);
}
__device__ __forceinline__ unsigned pack2(float a, float b) {
  return (unsigned)f2bf(a) | ((unsigned)f2bf(b) << 16);
}

// async global->LDS, 16 bytes per lane; LDS dst = wave-uniform base + lane*16
__device__ __forceinline__ void load_lds16(const void* g, void* l) {
  __builtin_amdgcn_global_load_lds(
      (const __attribute__((address_space(1))) void*)g,
      (__attribute__((address_space(3))) void*)l, 16, 0, 0);
}

// ---------------------------------------------------------------------------
// Fused preprocessing. Block ranges:
//   [0, 8192)        w1conv  : W1 fp32 -> W1p bf16 frag-major, COALESCED.
//                     Tile = 32 d-rows x 128 f-cols; phase-1 reads are 512 B
//                     contiguous per 32-lane half (vs 64 B scatter before).
//   [8192, 8448)     wsconv  : Ws -> Wsp (old 64x64 tile path).
//   [8448, 10496)    prep_x.
//   [10496, 10512)   routing.
// Shared 16.9 KB LDS arena -> 8 blocks/CU.
// ---------------------------------------------------------------------------
#define W1C_BLKS 8192             // h(16) x kb(32) x fb(16)
#define WS_BLKS  256
#define PX_BLKS  (TOK * 128 / 256)   // 2048
#define RT_BLKS  (TOK / 256)         // 16

__device__ void w1conv_body(int b, const float* __restrict__ W1,
                            unsigned short* __restrict__ W1p,
                            float (*Tf)[132]) {
  int fb = b & 15, kb = (b >> 4) & 31, h = b >> 9;
  const float* src = W1 + ((size_t)h * DD + kb * 32) * FF + fb * 128;
  const int tid = threadIdx.x;
  // Phase 1: 32 rows x 128 fp32, 512 B contiguous per 32-lane half.
  int row = tid >> 5, col4 = (tid & 31) * 4;
#pragma unroll
  for (int p = 0; p < 4; ++p) {
    float4 v = *(const float4*)(src + (size_t)(p * 8 + row) * FF + col4);
    *(float4*)&Tf[p * 8 + row][col4] = v;   // row stride 132*4=528 B, 16B-aligned
  }
  __syncthreads();
  // Phase 2: 2 frag chunks per thread; elem j = Tf[q*8+j][ntl*16+c].
  int nt0 = h * 128 + fb * 8;
#pragma unroll
  for (int cc = 0; cc < 2; ++cc) {
    int idx = tid + cc * 256;                 // ntl*64 + lane
    int lane2 = idx & 63, ntl = idx >> 6;     // ntl 0..7
    int nl = ntl * 16 + (lane2 & 15);
    int r0 = (lane2 >> 4) * 8;
    uint4 o;
    o.x = pack2(Tf[r0 + 0][nl], Tf[r0 + 1][nl]);
    o.y = pack2(Tf[r0 + 2][nl], Tf[r0 + 3][nl]);
    o.z = pack2(Tf[r0 + 4][nl], Tf[r0 + 5][nl]);
    o.w = pack2(Tf[r0 + 6][nl], Tf[r0 + 7][nl]);
    size_t chunk = ((size_t)(nt0 + ntl) * 32 + kb) * 64 + lane2;
    *(uint4*)(W1p + chunk * 8) = o;           // 1 KB contiguous per chunk
  }
}

// Old-style 64x64 tile converter (Ws only; 256 blocks, cost negligible).
__device__ void wtile_convert(
    const float* __restrict__ src, int stride,
    unsigned short* __restrict__ dstBase, int nt0, int kc0,
    unsigned short (*T)[70]) {
  const int tid = threadIdx.x;
  {
    int r = tid >> 2, cq = (tid & 3) * 16;
    const float* p = src + (size_t)r * stride + cq;
#pragma unroll
    for (int i = 0; i < 4; ++i) {
      float4 v = *(const float4*)(p + i * 4);
      *(unsigned*)&T[r][cq + i * 4 + 0] = pack2(v.x, v.y);
      *(unsigned*)&T[r][cq + i * 4 + 2] = pack2(v.z, v.w);
    }
  }
  __syncthreads();
#pragma unroll
  for (int cc = 0; cc < 2; ++cc) {
    int idx = tid + cc * 256;
    int lane2 = idx & 63, kcl = (idx >> 6) & 1, ntl = idx >> 7;
    int n_local = ntl * 16 + (lane2 & 15);
    int r0 = kcl * 32 + (lane2 >> 4) * 8;
    unsigned short e[8];
#pragma unroll
    for (int j = 0; j < 8; ++j) e[j] = T[r0 + j][n_local];
    uint4 o;
    o.x = (unsigned)e[0] | ((unsigned)e[1] << 16);
    o.y = (unsigned)e[2] | ((unsigned)e[3] << 16);
    o.z = (unsigned)e[4] | ((unsigned)e[5] << 16);
    o.w = (unsigned)e[6] | ((unsigned)e[7] << 16);
    size_t chunk = ((size_t)(nt0 + ntl) * 32 + (kc0 + kcl)) * 64 + lane2;
    *(uint4*)(dstBase + chunk * 8) = o;
  }
}

__global__ __launch_bounds__(256) void prep_all2(
    const int* __restrict__ selfies, const int* __restrict__ tasks,
    const float* __restrict__ values, const int* __restrict__ pmask,
    const float* __restrict__ emb_s, const float* __restrict__ emb_t,
    const float* __restrict__ val_vec, const float* __restrict__ Ws,
    const float* __restrict__ W1, const float* __restrict__ b2,
    unsigned short* __restrict__ Xb, unsigned short* __restrict__ Wsp,
    unsigned short* __restrict__ W1p,
    int* __restrict__ counts, int* __restrict__ lists, float* __restrict__ out) {
  __shared__ __align__(16) char smem[32 * 132 * 4];   // 16896 B arena
  int bid = blockIdx.x;
  if (bid < W1C_BLKS) {
    w1conv_body(bid, W1, W1p, (float (*)[132])smem);
  } else if (bid < W1C_BLKS + WS_BLKS) {
    int b2i = bid - W1C_BLKS;
    int fb = b2i & 15, kb = b2i >> 4;
    wtile_convert(Ws + (size_t)(kb * 64) * DD + fb * 64, DD, Wsp,
                  fb * 4, kb * 2, (unsigned short (*)[70])smem);
  } else if (bid < W1C_BLKS + WS_BLKS + PX_BLKS) {
    int gid = (bid - W1C_BLKS - WS_BLKS) * 256 + threadIdx.x;
    int kc = (gid & 127) * 8;
    int t  = gid >> 7;
    int sid = selfies[t], tsk = tasks[t];
    float v = values[t];
    float msk = pmask[t] ? 1.0f : 0.0f;
    const float* ps = emb_s + (size_t)sid * DD + kc;
    const float* pt = emb_t + (size_t)tsk * DD + kc;
    const float* pv = val_vec + kc;
    float r[8];
#pragma unroll
    for (int j = 0; j < 8; j += 4) {
      float4 a = *(const float4*)(ps + j);
      float4 b = *(const float4*)(pt + j);
      float4 c = *(const float4*)(pv + j);
      r[j + 0] = (a.x + b.x + v * c.x) * msk;
      r[j + 1] = (a.y + b.y + v * c.y) * msk;
      r[j + 2] = (a.z + b.z + v * c.z) * msk;
      r[j + 3] = (a.w + b.w + v * c.w) * msk;
    }
    uint4 o;
    o.x = pack2(r[0], r[1]); o.y = pack2(r[2], r[3]);
    o.z = pack2(r[4], r[5]); o.w = pack2(r[6], r[7]);
    *(uint4*)(Xb + (size_t)gid * 8) = o;
  } else {
    int t = (bid - W1C_BLKS - WS_BLKS - PX_BLKS) * 256 + threadIdx.x;
    if (t < TOK) {
      int task = tasks[t];
      if (task > 0) {
        int h = (task - 1) & (NH - 1);
        int pos = atomicAdd(&counts[h], 1);
        lists[h * TOK + pos] = t;
        out[t] = b2[h];
      } else {
        out[t] = 0.0f;
      }
    }
  }
}

// ---------------------------------------------------------------------------
// Stage 1: shared = gelu(X @ Ws + bs). Block = 64m x 128n, BK=32, 4 waves.
// QUAD-buffered LDS (48 KB -> 3 blocks/CU), 2-deep prefetch, vmcnt(6),
// one barrier per K-step. (exact round-3 proven structure, standalone)
// ---------------------------------------------------------------------------
__global__ __launch_bounds__(256) void gemm1_mfma(
    const unsigned short* __restrict__ Xb, const unsigned short* __restrict__ Wsp,
    const float* __restrict__ bs, unsigned short* __restrict__ shared_bf) {
  __shared__ __align__(16) unsigned short As[4][4 * 64 * 8];   // 4 x 4 KB
  __shared__ __align__(16) unsigned short Bs[4][8 * 64 * 8];   // 4 x 8 KB

  const int tid = threadIdx.x;
  const int lane = tid & 63, w = tid >> 6;
  const int m0 = blockIdx.x * 64;
  const int n0 = blockIdx.y * 128;
  const int q = lane >> 4, c = lane & 15;

  const unsigned short* aSrc = Xb + (size_t)(m0 + w * 16 + c) * DD + q * 8;
  const unsigned short* bBase = Wsp + ((size_t)(blockIdx.y * 8 + w * 2)) * 32 * 512 + lane * 8;
  f32x4 acc[4][2] = {};

  float bsv[2];
  bsv[0] = bs[n0 + w * 32 + c];
  bsv[1] = bs[n0 + w * 32 + 16 + c];
  asm volatile("" :: "v"(bsv[0]), "v"(bsv[1]));

  auto stage = [&](int buf, int kc2) {
    load_lds16(aSrc + kc2 * 32, As[buf] + (size_t)(w * 64 + lane) * 8);
    const unsigned short* bk = bBase + kc2 * 512;
    load_lds16(bk,            Bs[buf] + (size_t)((w * 2 + 0) * 64 + lane) * 8);
    load_lds16(bk + 16384,    Bs[buf] + (size_t)((w * 2 + 1) * 64 + lane) * 8);
  };
  auto compute = [&](int buf) {
    bf16x8 a[4], b[2];
#pragma unroll
    for (int mt = 0; mt < 4; ++mt)
      a[mt] = *(const bf16x8*)(As[buf] + (size_t)(mt * 64 + lane) * 8);
#pragma unroll
    for (int t = 0; t < 2; ++t)
      b[t] = *(const bf16x8*)(Bs[buf] + (size_t)((w * 2 + t) * 64 + lane) * 8);
    __builtin_amdgcn_s_setprio(1);
#pragma unroll
    for (int mt = 0; mt < 4; ++mt)
#pragma unroll
      for (int t = 0; t < 2; ++t)
        acc[mt][t] = __builtin_amdgcn_mfma_f32_16x16x32_bf16(a[mt], b[t], acc[mt][t], 0, 0, 0);
    __builtin_amdgcn_s_setprio(0);
  };

  stage(0, 0);
  stage(1, 1);
  for (int i = 0; i < 30; ++i) {
    stage((i + 2) & 3, i + 2);
    asm volatile("s_waitcnt vmcnt(6)" ::: "memory");
    __builtin_amdgcn_s_barrier();
    compute(i & 3);
    asm volatile("" ::: "memory");
  }
  asm volatile("s_waitcnt vmcnt(3)" ::: "memory");
  __builtin_amdgcn_s_barrier();
  compute(2);
  asm volatile("" ::: "memory");
  asm volatile("s_waitcnt vmcnt(0)" ::: "memory");
  __builtin_amdgcn_s_barrier();
  compute(3);

#pragma unroll
  for (int mt = 0; mt < 4; ++mt)
#pragma unroll
    for (int t = 0; t < 2; ++t)
#pragma unroll
      for (int r = 0; r < 4; ++r) {
        int row = m0 + mt * 16 + q * 4 + r;
        int col = n0 + w * 32 + t * 16 + c;
        shared_bf[(size_t)row * DD + col] = f2bf(gelu_f(acc[mt][t][r] + bsv[t]));
      }
}

// ---------------------------------------------------------------------------
// Stage 2: per-head MLP. Block = 64 tokens x 128 F, BK=32, 8 waves
// (512 threads): wave w owns nt=w (16 cols). 48 KB quad-buffer -> 3 blocks/
// CU x 8 waves = 24 waves/CU. Waves 0-3 stage A+B (vmcnt 4/2/0), waves 4-7
// stage B only (vmcnt 2/1/0). One barrier/K-step; XCD-pinned grid 2048.
// (round-7 version, unchanged)
// ---------------------------------------------------------------------------
__global__ __launch_bounds__(512) void gemm2_mfma(
    const unsigned short* __restrict__ shared_bf, const unsigned short* __restrict__ W1p,
    const float* __restrict__ b1, const float* __restrict__ W2,
    const int* __restrict__ counts, const int* __restrict__ lists,
    float* __restrict__ out) {
  const int id = blockIdx.x;
  const int xcd = id & 7, local_ = id >> 3;
  const int h = xcd + 8 * (local_ >> 7);
  const int rest = local_ & 127;
  const int fc = rest & 15;
  const int m0 = (rest >> 4) * 64;
  const int nt_h = counts[h];
  if (m0 >= nt_h) return;

  __shared__ __align__(16) unsigned short As[4][4 * 64 * 8];   // 4 x 4 KB
  __shared__ __align__(16) unsigned short Bs[4][8 * 64 * 8];   // 4 x 8 KB
  __shared__ int   stok[64];
  __shared__ float red[8][68];

  const int tid = threadIdx.x;
  const int lane = tid & 63, w = tid >> 6;
  const int q = lane >> 4, c = lane & 15;

  if (tid < 64) {
    int i = m0 + tid;
    stok[tid] = (i < nt_h) ? lists[h * TOK + i] : -1;
  }
  __syncthreads();

  int tokr = stok[(w & 3) * 16 + c];
  if (tokr < 0) tokr = 0;
  const unsigned short* aSrc = shared_bf + (size_t)tokr * DD + q * 8;
  const unsigned short* bBase =
      W1p + ((size_t)h * 128 + fc * 8 + w) * 32 * 512 + lane * 8;

  f32x4 acc[4] = {};

  float b1v = b1[(size_t)h * FF + fc * 128 + w * 16 + c];
  float w2v = W2[(size_t)h * FF + fc * 128 + w * 16 + c];
  asm volatile("" :: "v"(b1v), "v"(w2v));

  const bool loadsA = (w < 4);

  auto stage = [&](int buf, int kc2) {
    if (loadsA)
      load_lds16(aSrc + kc2 * 32, As[buf] + (size_t)(w * 64 + lane) * 8);
    load_lds16(bBase + kc2 * 512, Bs[buf] + (size_t)(w * 64 + lane) * 8);
  };
  auto compute = [&](int buf) {
    bf16x8 a[4], b;
#pragma unroll
    for (int mt = 0; mt < 4; ++mt)
      a[mt] = *(const bf16x8*)(As[buf] + (size_t)(mt * 64 + lane) * 8);
    b = *(const bf16x8*)(Bs[buf] + (size_t)(w * 64 + lane) * 8);
    __builtin_amdgcn_s_setprio(1);
#pragma unroll
    for (int mt = 0; mt < 4; ++mt)
      acc[mt] = __builtin_amdgcn_mfma_f32_16x16x32_bf16(a[mt], b, acc[mt], 0, 0, 0);
    __builtin_amdgcn_s_setprio(0);
  };

  stage(0, 0);
  stage(1, 1);
  for (int i = 0; i < 30; ++i) {
    stage((i + 2) & 3, i + 2);
    if (loadsA) { asm volatile("s_waitcnt vmcnt(4)" ::: "memory"); }
    else        { asm volatile("s_waitcnt vmcnt(2)" ::: "memory"); }
    __builtin_amdgcn_s_barrier();
    compute(i & 3);
    asm volatile("" ::: "memory");
  }
  if (loadsA) { asm volatile("s_waitcnt vmcnt(2)" ::: "memory"); }
  else        { asm volatile("s_waitcnt vmcnt(1)" ::: "memory"); }
  __builtin_amdgcn_s_barrier();
  compute(2);
  asm volatile("" ::: "memory");
  asm volatile("s_waitcnt vmcnt(0)" ::: "memory");
  __builtin_amdgcn_s_barrier();
  compute(3);

#pragma unroll
  for (int mt = 0; mt < 4; ++mt)
#pragma unroll
    for (int r = 0; r < 4; ++r) {
      float s = gelu_f(acc[mt][r] + b1v) * w2v;
      s += __shfl_xor(s, 1);
      s += __shfl_xor(s, 2);
      s += __shfl_xor(s, 4);
      s += __shfl_xor(s, 8);
      if (c == 0) red[w][mt * 16 + q * 4 + r] = s;
    }
  __syncthreads();

  if (tid < 64) {
    int t = stok[tid];
    if (t >= 0) {
      float s = 0.0f;
#pragma unroll
      for (int ww = 0; ww < 8; ++ww) s += red[ww][tid];
      atomicAdd(&out[t], s);
    }
  }
}

// ---------------------------------------------------------------------------
extern "C" void kernel_launch(void* const* d_in, const int* in_sizes, int n_in,
                              void* d_out, int out_size, void* d_ws, size_t ws_size,
                              hipStream_t stream) {
  const int*   selfies = (const int*)d_in[0];
  const int*   tasks   = (const int*)d_in[1];
  const float* values  = (const float*)d_in[2];
  const int*   pmask   = (const int*)d_in[3];
  const float* emb_s   = (const float*)d_in[4];
  const float* emb_t   = (const float*)d_in[5];
  const float* val_vec = (const float*)d_in[6];
  const float* Ws      = (const float*)d_in[7];
  const float* bs      = (const float*)d_in[8];
  const float* W1      = (const float*)d_in[9];
  const float* b1      = (const float*)d_in[10];
  const float* W2      = (const float*)d_in[11];
  const float* b2      = (const float*)d_in[12];
  float* out = (float*)d_out;

  // Workspace layout (all 256-B aligned):
  //   Xb        bf16 [4096][1024]            8 MB
  //   shared_bf bf16 [4096][1024]            8 MB
  //   Wsp       bf16 frag-major              2 MB
  //   W1p       bf16 frag-major             64 MB
  //   counts    int[16] ; lists int[16*4096]
  char* ws = (char*)d_ws;
  unsigned short* Xb        = (unsigned short*)ws;
  unsigned short* shared_bf = (unsigned short*)(ws + (8u << 20));
  unsigned short* Wsp       = (unsigned short*)(ws + (16u << 20));
  unsigned short* W1p       = (unsigned short*)(ws + (18u << 20));
  int* counts = (int*)(ws + (82u << 20));
  int* lists  = (int*)(ws + (82u << 20) + 256);

  hipMemsetAsync(counts, 0, NH * sizeof(int), stream);
  prep_all2<<<W1C_BLKS + WS_BLKS + PX_BLKS + RT_BLKS, 256, 0, stream>>>(
      selfies, tasks, values, pmask, emb_s, emb_t, val_vec, Ws, W1, b2,
      Xb, Wsp, W1p, counts, lists, out);
  gemm1_mfma<<<dim3(TOK / 64, DD / 128), 256, 0, stream>>>(Xb, Wsp, bs, shared_bf);
  gemm2_mfma<<<2048, 512, 0, stream>>>(shared_bf, W1p, b1, W2,
                                       counts, lists, out);
}

// Round 10
// 298.485 us; speedup vs baseline: 1.0857x; 1.0110x over previous
//
#include <hip/hip_runtime.h>
#include <hip/hip_bf16.h>

// B=8, S=512 -> TOK=4096 tokens, D=1024, F=2048, H=16 heads, O=1.
#define TOK 4096
#define DD  1024
#define FF  2048
#define NH  16

typedef short bf16x8 __attribute__((ext_vector_type(8)));
typedef float f32x4  __attribute__((ext_vector_type(4)));

__device__ __forceinline__ float gelu_f(float x) {
  float u = 0.7978845608028654f * (x + 0.044715f * x * x * x);
  float e = __expf(2.0f * u);
  return 0.5f * x * (2.0f - 2.0f / (e + 1.0f));
}

// fp32 -> bf16 round-to-nearest-even
__device__ __forceinline__ unsigned short f2bf(float f) {
  union { float f; unsigned u; } v; v.f = f;
  unsigned r = v.u + 0x7FFF + ((v.u >> 16) & 1);
  return (unsigned short)(r >> 16);
}
__device__ __forceinline__ unsigned pack2(float a, float b) {
  return (unsigned)f2bf(a) | ((unsigned)f2bf(b) << 16);
}

// async global->LDS, 16 bytes per lane; LDS dst = wave-uniform base + lane*16
__device__ __forceinline__ void load_lds16(const void* g, void* l) {
  __builtin_amdgcn_global_load_lds(
      (const __attribute__((address_space(1))) void*)g,
      (__attribute__((address_space(3))) void*)l, 16, 0, 0);
}

// ---------------------------------------------------------------------------
// W1 tile converter (coalesced, round-8 proven): 32 d-rows x 128 f-cols fp32
// -> bf16 frag-major. Phase-1 reads 512 B contiguous per 32-lane half.
// ---------------------------------------------------------------------------
__device__ void w1conv_body(int b, const float* __restrict__ W1,
                            unsigned short* __restrict__ W1p,
                            float (*Tf)[132]) {
  int fb = b & 15, kb = (b >> 4) & 31, h = b >> 9;
  const float* src = W1 + ((size_t)h * DD + kb * 32) * FF + fb * 128;
  const int tid = threadIdx.x;
  int row = tid >> 5, col4 = (tid & 31) * 4;
#pragma unroll
  for (int p = 0; p < 4; ++p) {
    float4 v = *(const float4*)(src + (size_t)(p * 8 + row) * FF + col4);
    *(float4*)&Tf[p * 8 + row][col4] = v;
  }
  __syncthreads();
  int nt0 = h * 128 + fb * 8;
#pragma unroll
  for (int cc = 0; cc < 2; ++cc) {
    int idx = tid + cc * 256;                 // ntl*64 + lane
    int lane2 = idx & 63, ntl = idx >> 6;
    int nl = ntl * 16 + (lane2 & 15);
    int r0 = (lane2 >> 4) * 8;
    uint4 o;
    o.x = pack2(Tf[r0 + 0][nl], Tf[r0 + 1][nl]);
    o.y = pack2(Tf[r0 + 2][nl], Tf[r0 + 3][nl]);
    o.z = pack2(Tf[r0 + 4][nl], Tf[r0 + 5][nl]);
    o.w = pack2(Tf[r0 + 6][nl], Tf[r0 + 7][nl]);
    size_t chunk = ((size_t)(nt0 + ntl) * 32 + kb) * 64 + lane2;
    *(uint4*)(W1p + chunk * 8) = o;
  }
}

// Old-style 64x64 tile converter (Ws only; round-7 proven).
__device__ void wtile_convert(
    const float* __restrict__ src, int stride,
    unsigned short* __restrict__ dstBase, int nt0, int kc0,
    unsigned short (*T)[70]) {
  const int tid = threadIdx.x;
  {
    int r = tid >> 2, cq = (tid & 3) * 16;
    const float* p = src + (size_t)r * stride + cq;
#pragma unroll
    for (int i = 0; i < 4; ++i) {
      float4 v = *(const float4*)(p + i * 4);
      *(unsigned*)&T[r][cq + i * 4 + 0] = pack2(v.x, v.y);
      *(unsigned*)&T[r][cq + i * 4 + 2] = pack2(v.z, v.w);
    }
  }
  __syncthreads();
#pragma unroll
  for (int cc = 0; cc < 2; ++cc) {
    int idx = tid + cc * 256;
    int lane2 = idx & 63, kcl = (idx >> 6) & 1, ntl = idx >> 7;
    int n_local = ntl * 16 + (lane2 & 15);
    int r0 = kcl * 32 + (lane2 >> 4) * 8;
    unsigned short e[8];
#pragma unroll
    for (int j = 0; j < 8; ++j) e[j] = T[r0 + j][n_local];
    uint4 o;
    o.x = (unsigned)e[0] | ((unsigned)e[1] << 16);
    o.y = (unsigned)e[2] | ((unsigned)e[3] << 16);
    o.z = (unsigned)e[4] | ((unsigned)e[5] << 16);
    o.w = (unsigned)e[6] | ((unsigned)e[7] << 16);
    size_t chunk = ((size_t)(nt0 + ntl) * 32 + (kc0 + kcl)) * 64 + lane2;
    *(uint4*)(dstBase + chunk * 8) = o;
  }
}

// ---------------------------------------------------------------------------
// prep_small (round-7 proven): Ws conv (256) + prep_x (2048) + routing (16).
// ---------------------------------------------------------------------------
#define WS_BLKS 256
#define PX_BLKS (TOK * 128 / 256)   // 2048

__global__ __launch_bounds__(256) void prep_small(
    const int* __restrict__ selfies, const int* __restrict__ tasks,
    const float* __restrict__ values, const int* __restrict__ pmask,
    const float* __restrict__ emb_s, const float* __restrict__ emb_t,
    const float* __restrict__ val_vec, const float* __restrict__ Ws,
    const float* __restrict__ b2,
    unsigned short* __restrict__ Xb, unsigned short* __restrict__ Wsp,
    int* __restrict__ counts, int* __restrict__ lists, float* __restrict__ out) {
  __shared__ unsigned short T[64][70];
  int bid = blockIdx.x;
  if (bid < WS_BLKS) {
    int fb = bid & 15, kb = bid >> 4;
    wtile_convert(Ws + (size_t)(kb * 64) * DD + fb * 64, DD, Wsp,
                  fb * 4, kb * 2, T);
  } else if (bid < WS_BLKS + PX_BLKS) {
    int gid = (bid - WS_BLKS) * 256 + threadIdx.x;
    int kc = (gid & 127) * 8;
    int t  = gid >> 7;
    int sid = selfies[t], tsk = tasks[t];
    float v = values[t];
    float msk = pmask[t] ? 1.0f : 0.0f;
    const float* ps = emb_s + (size_t)sid * DD + kc;
    const float* pt = emb_t + (size_t)tsk * DD + kc;
    const float* pv = val_vec + kc;
    float r[8];
#pragma unroll
    for (int j = 0; j < 8; j += 4) {
      float4 a = *(const float4*)(ps + j);
      float4 b = *(const float4*)(pt + j);
      float4 c = *(const float4*)(pv + j);
      r[j + 0] = (a.x + b.x + v * c.x) * msk;
      r[j + 1] = (a.y + b.y + v * c.y) * msk;
      r[j + 2] = (a.z + b.z + v * c.z) * msk;
      r[j + 3] = (a.w + b.w + v * c.w) * msk;
    }
    uint4 o;
    o.x = pack2(r[0], r[1]); o.y = pack2(r[2], r[3]);
    o.z = pack2(r[4], r[5]); o.w = pack2(r[6], r[7]);
    *(uint4*)(Xb + (size_t)gid * 8) = o;
  } else {
    int t = (bid - WS_BLKS - PX_BLKS) * 256 + threadIdx.x;
    if (t < TOK) {
      int task = tasks[t];
      if (task > 0) {
        int h = (task - 1) & (NH - 1);
        int pos = atomicAdd(&counts[h], 1);
        lists[h * TOK + pos] = t;
        out[t] = b2[h];
      } else {
        out[t] = 0.0f;
      }
    }
  }
}

// ---------------------------------------------------------------------------
// Fused launch (round-6 proven composition + round-8 proven coalesced conv):
// blocks [0,512) = gemm1 tiles (64m x 128n, BK=32, quad-buffer, vmcnt(6),
// one barrier/K-step); blocks [512, 512+8192) = coalesced W1 -> W1p tiles.
// gemm1 (~30 us) hides under the W1 conversion (~40 us) instead of
// serializing after it. Shared 48 KB LDS arena.
// ---------------------------------------------------------------------------
#define G1_BLKS  512
#define W1_BLKS  8192             // h(16) x kb(32) x fb(16)

__device__ void gemm1_body(
    int bid, const unsigned short* __restrict__ Xb,
    const unsigned short* __restrict__ Wsp, const float* __restrict__ bs,
    unsigned short* __restrict__ shared_bf, char* smem) {
  unsigned short* As = (unsigned short*)smem;            // 4 bufs x 2048 u16
  unsigned short* Bs = (unsigned short*)(smem + 16384);  // 4 bufs x 4096 u16

  const int tid = threadIdx.x;
  const int lane = tid & 63, w = tid >> 6;
  const int m0 = (bid & 63) * 64;
  const int n0 = (bid >> 6) * 128;
  const int q = lane >> 4, c = lane & 15;

  const unsigned short* aSrc = Xb + (size_t)(m0 + w * 16 + c) * DD + q * 8;
  const unsigned short* bBase =
      Wsp + ((size_t)((bid >> 6) * 8 + w * 2)) * 32 * 512 + lane * 8;
  f32x4 acc[4][2] = {};

  float bsv[2];
  bsv[0] = bs[n0 + w * 32 + c];
  bsv[1] = bs[n0 + w * 32 + 16 + c];
  asm volatile("" :: "v"(bsv[0]), "v"(bsv[1]));

  auto stage = [&](int buf, int kc2) {
    load_lds16(aSrc + kc2 * 32, As + buf * 2048 + (size_t)(w * 64 + lane) * 8);
    const unsigned short* bk = bBase + kc2 * 512;
    load_lds16(bk,         Bs + buf * 4096 + (size_t)((w * 2 + 0) * 64 + lane) * 8);
    load_lds16(bk + 16384, Bs + buf * 4096 + (size_t)((w * 2 + 1) * 64 + lane) * 8);
  };
  auto compute = [&](int buf) {
    bf16x8 a[4], b[2];
#pragma unroll
    for (int mt = 0; mt < 4; ++mt)
      a[mt] = *(const bf16x8*)(As + buf * 2048 + (size_t)(mt * 64 + lane) * 8);
#pragma unroll
    for (int t = 0; t < 2; ++t)
      b[t] = *(const bf16x8*)(Bs + buf * 4096 + (size_t)((w * 2 + t) * 64 + lane) * 8);
    __builtin_amdgcn_s_setprio(1);
#pragma unroll
    for (int mt = 0; mt < 4; ++mt)
#pragma unroll
      for (int t = 0; t < 2; ++t)
        acc[mt][t] = __builtin_amdgcn_mfma_f32_16x16x32_bf16(a[mt], b[t], acc[mt][t], 0, 0, 0);
    __builtin_amdgcn_s_setprio(0);
  };

  stage(0, 0);
  stage(1, 1);
  for (int i = 0; i < 30; ++i) {
    stage((i + 2) & 3, i + 2);
    asm volatile("s_waitcnt vmcnt(6)" ::: "memory");
    __builtin_amdgcn_s_barrier();
    compute(i & 3);
    asm volatile("" ::: "memory");
  }
  asm volatile("s_waitcnt vmcnt(3)" ::: "memory");
  __builtin_amdgcn_s_barrier();
  compute(2);
  asm volatile("" ::: "memory");
  asm volatile("s_waitcnt vmcnt(0)" ::: "memory");
  __builtin_amdgcn_s_barrier();
  compute(3);

#pragma unroll
  for (int mt = 0; mt < 4; ++mt)
#pragma unroll
    for (int t = 0; t < 2; ++t)
#pragma unroll
      for (int r = 0; r < 4; ++r) {
        int row = m0 + mt * 16 + q * 4 + r;
        int col = n0 + w * 32 + t * 16 + c;
        shared_bf[(size_t)row * DD + col] = f2bf(gelu_f(acc[mt][t][r] + bsv[t]));
      }
}

__global__ __launch_bounds__(256) void gemm1_w1prep(
    const unsigned short* __restrict__ Xb, const unsigned short* __restrict__ Wsp,
    const float* __restrict__ bs, unsigned short* __restrict__ shared_bf,
    const float* __restrict__ W1, unsigned short* __restrict__ W1p) {
  __shared__ __align__(16) char smem[49152];
  int bid = blockIdx.x;
  if (bid < G1_BLKS) {
    gemm1_body(bid, Xb, Wsp, bs, shared_bf, smem);
  } else {
    w1conv_body(bid - G1_BLKS, W1, W1p, (float (*)[132])smem);
  }
}

// ---------------------------------------------------------------------------
// Stage 2 (round-7/8 proven): 64 tok x 128 F, BK=32, 8 waves (512 thr),
// wave w owns nt=w. 48 KB quad-buffer -> 3 blocks/CU x 8 waves = 24 waves/CU.
// Waves 0-3 stage A+B (vmcnt 4/2/0), waves 4-7 stage B only (vmcnt 2/1/0).
// One barrier/K-step; XCD-pinned grid 2048.
// ---------------------------------------------------------------------------
__global__ __launch_bounds__(512) void gemm2_mfma(
    const unsigned short* __restrict__ shared_bf, const unsigned short* __restrict__ W1p,
    const float* __restrict__ b1, const float* __restrict__ W2,
    const int* __restrict__ counts, const int* __restrict__ lists,
    float* __restrict__ out) {
  const int id = blockIdx.x;
  const int xcd = id & 7, local_ = id >> 3;
  const int h = xcd + 8 * (local_ >> 7);
  const int rest = local_ & 127;
  const int fc = rest & 15;
  const int m0 = (rest >> 4) * 64;
  const int nt_h = counts[h];
  if (m0 >= nt_h) return;

  __shared__ __align__(16) unsigned short As[4][4 * 64 * 8];   // 4 x 4 KB
  __shared__ __align__(16) unsigned short Bs[4][8 * 64 * 8];   // 4 x 8 KB
  __shared__ int   stok[64];
  __shared__ float red[8][68];

  const int tid = threadIdx.x;
  const int lane = tid & 63, w = tid >> 6;
  const int q = lane >> 4, c = lane & 15;

  if (tid < 64) {
    int i = m0 + tid;
    stok[tid] = (i < nt_h) ? lists[h * TOK + i] : -1;
  }
  __syncthreads();

  int tokr = stok[(w & 3) * 16 + c];
  if (tokr < 0) tokr = 0;
  const unsigned short* aSrc = shared_bf + (size_t)tokr * DD + q * 8;
  const unsigned short* bBase =
      W1p + ((size_t)h * 128 + fc * 8 + w) * 32 * 512 + lane * 8;

  f32x4 acc[4] = {};

  float b1v = b1[(size_t)h * FF + fc * 128 + w * 16 + c];
  float w2v = W2[(size_t)h * FF + fc * 128 + w * 16 + c];
  asm volatile("" :: "v"(b1v), "v"(w2v));

  const bool loadsA = (w < 4);

  auto stage = [&](int buf, int kc2) {
    if (loadsA)
      load_lds16(aSrc + kc2 * 32, As[buf] + (size_t)(w * 64 + lane) * 8);
    load_lds16(bBase + kc2 * 512, Bs[buf] + (size_t)(w * 64 + lane) * 8);
  };
  auto compute = [&](int buf) {
    bf16x8 a[4], b;
#pragma unroll
    for (int mt = 0; mt < 4; ++mt)
      a[mt] = *(const bf16x8*)(As[buf] + (size_t)(mt * 64 + lane) * 8);
    b = *(const bf16x8*)(Bs[buf] + (size_t)(w * 64 + lane) * 8);
    __builtin_amdgcn_s_setprio(1);
#pragma unroll
    for (int mt = 0; mt < 4; ++mt)
      acc[mt] = __builtin_amdgcn_mfma_f32_16x16x32_bf16(a[mt], b, acc[mt], 0, 0, 0);
    __builtin_amdgcn_s_setprio(0);
  };

  stage(0, 0);
  stage(1, 1);
  for (int i = 0; i < 30; ++i) {
    stage((i + 2) & 3, i + 2);
    if (loadsA) { asm volatile("s_waitcnt vmcnt(4)" ::: "memory"); }
    else        { asm volatile("s_waitcnt vmcnt(2)" ::: "memory"); }
    __builtin_amdgcn_s_barrier();
    compute(i & 3);
    asm volatile("" ::: "memory");
  }
  if (loadsA) { asm volatile("s_waitcnt vmcnt(2)" ::: "memory"); }
  else        { asm volatile("s_waitcnt vmcnt(1)" ::: "memory"); }
  __builtin_amdgcn_s_barrier();
  compute(2);
  asm volatile("" ::: "memory");
  asm volatile("s_waitcnt vmcnt(0)" ::: "memory");
  __builtin_amdgcn_s_barrier();
  compute(3);

#pragma unroll
  for (int mt = 0; mt < 4; ++mt)
#pragma unroll
    for (int r = 0; r < 4; ++r) {
      float s = gelu_f(acc[mt][r] + b1v) * w2v;
      s += __shfl_xor(s, 1);
      s += __shfl_xor(s, 2);
      s += __shfl_xor(s, 4);
      s += __shfl_xor(s, 8);
      if (c == 0) red[w][mt * 16 + q * 4 + r] = s;
    }
  __syncthreads();

  if (tid < 64) {
    int t = stok[tid];
    if (t >= 0) {
      float s = 0.0f;
#pragma unroll
      for (int ww = 0; ww < 8; ++ww) s += red[ww][tid];
      atomicAdd(&out[t], s);
    }
  }
}

// ---------------------------------------------------------------------------
extern "C" void kernel_launch(void* const* d_in, const int* in_sizes, int n_in,
                              void* d_out, int out_size, void* d_ws, size_t ws_size,
                              hipStream_t stream) {
  const int*   selfies = (const int*)d_in[0];
  const int*   tasks   = (const int*)d_in[1];
  const float* values  = (const float*)d_in[2];
  const int*   pmask   = (const int*)d_in[3];
  const float* emb_s   = (const float*)d_in[4];
  const float* emb_t   = (const float*)d_in[5];
  const float* val_vec = (const float*)d_in[6];
  const float* Ws      = (const float*)d_in[7];
  const float* bs      = (const float*)d_in[8];
  const float* W1      = (const float*)d_in[9];
  const float* b1      = (const float*)d_in[10];
  const float* W2      = (const float*)d_in[11];
  const float* b2      = (const float*)d_in[12];
  float* out = (float*)d_out;

  // Workspace layout (all 256-B aligned):
  //   Xb        bf16 [4096][1024]            8 MB
  //   shared_bf bf16 [4096][1024]            8 MB
  //   Wsp       bf16 frag-major              2 MB
  //   W1p       bf16 frag-major             64 MB
  //   counts    int[16] ; lists int[16*4096]
  char* ws = (char*)d_ws;
  unsigned short* Xb        = (unsigned short*)ws;
  unsigned short* shared_bf = (unsigned short*)(ws + (8u << 20));
  unsigned short* Wsp       = (unsigned short*)(ws + (16u << 20));
  unsigned short* W1p       = (unsigned short*)(ws + (18u << 20));
  int* counts = (int*)(ws + (82u << 20));
  int* lists  = (int*)(ws + (82u << 20) + 256);

  hipMemsetAsync(counts, 0, NH * sizeof(int), stream);
  prep_small<<<WS_BLKS + PX_BLKS + TOK / 256, 256, 0, stream>>>(
      selfies, tasks, values, pmask, emb_s, emb_t, val_vec, Ws, b2,
      Xb, Wsp, counts, lists, out);
  gemm1_w1prep<<<G1_BLKS + W1_BLKS, 256, 0, stream>>>(
      Xb, Wsp, bs, shared_bf, W1, W1p);
  gemm2_mfma<<<2048, 512, 0, stream>>>(shared_bf, W1p, b1, W2,
                                       counts, lists, out);
}